// Round 17
// baseline (148.039 us; speedup 1.0000x reference)
//
#include <hip/hip_runtime.h>
#include <hip/hip_bf16.h>
#include <math.h>

typedef float v4f __attribute__((ext_vector_type(4)));
typedef short bf16x8 __attribute__((ext_vector_type(8)));   // 8 bf16 (4 VGPR)
typedef float f32x16 __attribute__((ext_vector_type(16)));

#define BATCH 4
#define NQ 4096
#define NK 4096
#define DIM 256
#define INNER 64
#define NEG_INF (-3.0e38f)
#define CAP 64

// ---------- K1: proj (blocks 0-1023) + bulk zero-fill (blocks 1024-3071) -----
// proj: bid<512 -> q slab (row-major bf16), 512<=bid<1024 -> k slab
// (fragment-major bf16 [tile32][d:4][hi:2][row:32][e:8]). Bit-identical math.
// fill blocks zero d_out concurrently with proj (store-only, full rate).
__global__ __launch_bounds__(256) void projfill_kernel(
    const float* __restrict__ q, const float* __restrict__ k,
    const float* __restrict__ Wq, const float* __restrict__ Wk,
    float* __restrict__ qh, float* __restrict__ kh,
    ushort* __restrict__ qhb, ushort* __restrict__ khb,
    float* __restrict__ outz)
{
  __shared__ float xs[32 * 260];
  const int bid = blockIdx.x;
  const int t = threadIdx.x;

  if (bid >= 1024) {
    v4f* zp = reinterpret_cast<v4f*>(outz);
    const v4f z = {0.f, 0.f, 0.f, 0.f};
    size_t idx = (size_t)(bid - 1024) * 256 + t;     // 524288 threads
    #pragma unroll 8
    for (int it = 0; it < 32; ++it)
      zp[idx + (size_t)it * 524288] = z;
    return;
  }

  const bool isq = bid < 512;
  const float* X   = isq ? q : k;
  const float* W   = isq ? Wq : Wk;
  float*   out     = isq ? qh : kh;
  const float scale = isq ? 0.125f : 1.0f;
  const int row0 = (isq ? bid : bid - 512) * 32;

  #pragma unroll
  for (int it = 0; it < 8; ++it) {
    int idx = it * 256 + t;
    int r = idx >> 6, dq = idx & 63;
    v4f v = *reinterpret_cast<const v4f*>(X + (size_t)(row0 + r) * DIM + dq * 4);
    *reinterpret_cast<v4f*>(&xs[r * 260 + dq * 4]) = v;
  }
  __syncthreads();

  const int i0 = (t & 15) * 4;
  const int rg = t >> 4;
  float acc[2][4];
  #pragma unroll
  for (int p = 0; p < 2; ++p)
    #pragma unroll
    for (int i = 0; i < 4; ++i) acc[p][i] = 0.f;

  for (int d0 = 0; d0 < DIM; d0 += 4) {
    v4f w0 = *reinterpret_cast<const v4f*>(W + (d0 + 0) * INNER + i0);
    v4f w1 = *reinterpret_cast<const v4f*>(W + (d0 + 1) * INNER + i0);
    v4f w2 = *reinterpret_cast<const v4f*>(W + (d0 + 2) * INNER + i0);
    v4f w3 = *reinterpret_cast<const v4f*>(W + (d0 + 3) * INNER + i0);
    #pragma unroll
    for (int p = 0; p < 2; ++p) {
      v4f x = *reinterpret_cast<const v4f*>(&xs[(rg + 16 * p) * 260 + d0]);
      #pragma unroll
      for (int i = 0; i < 4; ++i) {
        float bs = x[0] * w0[i];                 // bit-exact blocked order
        bs = fmaf(x[1], w1[i], bs);
        bs = fmaf(x[2], w2[i], bs);
        bs = fmaf(x[3], w3[i], bs);
        acc[p][i] += bs;
      }
    }
  }

  const int d  = i0 >> 4;
  const int hi = (i0 >> 3) & 1;
  const int e0 = i0 & 7;
  #pragma unroll
  for (int p = 0; p < 2; ++p) {
    v4f o;
    ushort ob[4];
    #pragma unroll
    for (int i = 0; i < 4; ++i) {
      o[i] = acc[p][i] * scale;
      __hip_bfloat16 h = __float2bfloat16(o[i]);
      ob[i] = *reinterpret_cast<ushort*>(&h);
    }
    int rr = rg + 16 * p;
    size_t row = (size_t)(row0 + rr);
    *reinterpret_cast<v4f*>(out + row * INNER + i0) = o;
    if (isq) {
      *reinterpret_cast<uint2*>(qhb + row * INNER + i0) =
          *reinterpret_cast<uint2*>(ob);
    } else {
      size_t off = (size_t)(bid - 512) * 2048 + d * 512 + hi * 256 + rr * 8 + e0;
      *reinterpret_cast<uint2*>(khb + off) = *reinterpret_cast<uint2*>(ob);
    }
  }
}

// ---------- cold-path sorted inserts -----------------------------------------
__device__ __forceinline__ void insert5(float (&v)[5], int (&ix)[5], float x, int xi) {
  bool g0 = x > v[0], g1 = x > v[1], g2 = x > v[2], g3 = x > v[3];
  v[4]  = g3 ? v[3] : x;                 ix[4] = g3 ? ix[3] : xi;
  v[3]  = g3 ? (g2 ? v[2] : x) : v[3];   ix[3] = g3 ? (g2 ? ix[2] : xi) : ix[3];
  v[2]  = g2 ? (g1 ? v[1] : x) : v[2];   ix[2] = g2 ? (g1 ? ix[1] : xi) : ix[2];
  v[1]  = g1 ? (g0 ? v[0] : x) : v[1];   ix[1] = g1 ? (g0 ? ix[0] : xi) : ix[1];
  v[0]  = g0 ? x : v[0];                 ix[0] = g0 ? xi : ix[0];
}

__device__ __forceinline__ void insert8v(float (&v)[8], float x) {
  bool g0 = x > v[0], g1 = x > v[1], g2 = x > v[2], g3 = x > v[3];
  bool g4 = x > v[4], g5 = x > v[5], g6 = x > v[6];
  v[7] = g6 ? v[6] : x;
  v[6] = g6 ? (g5 ? v[5] : x) : v[6];
  v[5] = g5 ? (g4 ? v[4] : x) : v[5];
  v[4] = g4 ? (g3 ? v[3] : x) : v[4];
  v[3] = g3 ? (g2 ? v[2] : x) : v[3];
  v[2] = g2 ? (g1 ? v[1] : x) : v[2];
  v[1] = g1 ? (g0 ? v[0] : x) : v[1];
  v[0] = g0 ? x : v[0];
}

// ---------- K2: 2-pass MFMA filter, QT=64 @ 1024 thr (16 waves) --------------
// 256 blocks x 1024 thr; block owns 64 q-rows; wave qg in [0,16) owns 8 tiles
// x 2 q-row-sets (A=rows 0-31, B=32-63). khb scan per block unchanged in
// shape but blocks/batch halve (64) -> per-XCD L2 traffic halves vs QT=32,
// at the SAME 16 waves/CU occupancy (fixes r15's failure mode).
// tau[row] = 8th-largest of 32 strip maxes (superset proof unchanged).
__global__ __launch_bounds__(1024, 1) void filter_kernel(
    const ushort* __restrict__ qhb, const ushort* __restrict__ khb,
    const float* __restrict__ qh, const float* __restrict__ kh,
    float* __restrict__ out)
{
  __shared__ float qhf[64][68];
  __shared__ float sm[64][32];
  __shared__ float tau[64];
  __shared__ int   cnt[64];
  __shared__ int   cand[64][CAP];
  __shared__ float exactv[64][CAP];
  __shared__ float w5[64][5];
  __shared__ int   id5[64][6];

  const int t   = threadIdx.x;
  const int bid = blockIdx.x;
  const int wg  = (bid & 7) * 32 + (bid >> 3);   // XCD swizzle (256 = 8*32)
  const int b   = wg >> 6;                       // 64 blocks per batch
  const int q0  = (wg & 63) * 64;
  const int qg  = t >> 6;                        // wave 0..15
  const int kg  = t & 63;
  const int ln  = kg & 31;
  const int hi  = kg >> 5;

  // stage f32 q rows for rescore: 1024 thr x 4 f32 -> 64 rows x 64 cols
  {
    int row = t >> 4, c4 = (t & 15) * 4;
    const float* src = qh + ((size_t)b * NQ + q0 + row) * INNER + c4;
    *reinterpret_cast<v4f*>(&qhf[row][c4]) = *reinterpret_cast<const v4f*>(src);
  }
  if (t < 64) cnt[t] = 0;

  // q fragments, set A (rows q0+0..31) and set B (rows q0+32..63)
  const ushort* qptrA = qhb + ((size_t)b * NQ + q0 + ln) * INNER + hi * 8;
  const ushort* qptrB = qptrA + 32 * INNER;
  bf16x8 qfA0 = *reinterpret_cast<const bf16x8*>(qptrA);
  bf16x8 qfA1 = *reinterpret_cast<const bf16x8*>(qptrA + 16);
  bf16x8 qfA2 = *reinterpret_cast<const bf16x8*>(qptrA + 32);
  bf16x8 qfA3 = *reinterpret_cast<const bf16x8*>(qptrA + 48);
  bf16x8 qfB0 = *reinterpret_cast<const bf16x8*>(qptrB);
  bf16x8 qfB1 = *reinterpret_cast<const bf16x8*>(qptrB + 16);
  bf16x8 qfB2 = *reinterpret_cast<const bf16x8*>(qptrB + 32);
  bf16x8 qfB3 = *reinterpret_cast<const bf16x8*>(qptrB + 48);

  // wave qg's 8 tiles, fragment-major
  const ushort* ktile = khb + ((size_t)b * 128 + qg * 8) * 2048;

  // ---- Pass 1: branchless strip max (both q-sets per fragment load) -------
  float smaxA = NEG_INF, smaxB = NEG_INF;
  for (int t8 = 0; t8 < 8; ++t8) {
    const ushort* tb = ktile + (size_t)t8 * 2048;
    bf16x8 k0 = *reinterpret_cast<const bf16x8*>(tb +        kg * 8);
    bf16x8 k1 = *reinterpret_cast<const bf16x8*>(tb +  512 + kg * 8);
    bf16x8 k2 = *reinterpret_cast<const bf16x8*>(tb + 1024 + kg * 8);
    bf16x8 k3 = *reinterpret_cast<const bf16x8*>(tb + 1536 + kg * 8);

    f32x16 aA = {0.f,0.f,0.f,0.f,0.f,0.f,0.f,0.f,0.f,0.f,0.f,0.f,0.f,0.f,0.f,0.f};
    f32x16 aB = {0.f,0.f,0.f,0.f,0.f,0.f,0.f,0.f,0.f,0.f,0.f,0.f,0.f,0.f,0.f,0.f};
    aA = __builtin_amdgcn_mfma_f32_32x32x16_bf16(k0, qfA0, aA, 0, 0, 0);
    aA = __builtin_amdgcn_mfma_f32_32x32x16_bf16(k1, qfA1, aA, 0, 0, 0);
    aA = __builtin_amdgcn_mfma_f32_32x32x16_bf16(k2, qfA2, aA, 0, 0, 0);
    aA = __builtin_amdgcn_mfma_f32_32x32x16_bf16(k3, qfA3, aA, 0, 0, 0);
    aB = __builtin_amdgcn_mfma_f32_32x32x16_bf16(k0, qfB0, aB, 0, 0, 0);
    aB = __builtin_amdgcn_mfma_f32_32x32x16_bf16(k1, qfB1, aB, 0, 0, 0);
    aB = __builtin_amdgcn_mfma_f32_32x32x16_bf16(k2, qfB2, aB, 0, 0, 0);
    aB = __builtin_amdgcn_mfma_f32_32x32x16_bf16(k3, qfB3, aB, 0, 0, 0);

    float a0 = fmaxf(fmaxf(aA[0],  aA[1]),  fmaxf(aA[2],  aA[3]));
    float a1 = fmaxf(fmaxf(aA[4],  aA[5]),  fmaxf(aA[6],  aA[7]));
    float a2 = fmaxf(fmaxf(aA[8],  aA[9]),  fmaxf(aA[10], aA[11]));
    float a3 = fmaxf(fmaxf(aA[12], aA[13]), fmaxf(aA[14], aA[15]));
    smaxA = fmaxf(smaxA, fmaxf(fmaxf(a0, a1), fmaxf(a2, a3)));
    float b0 = fmaxf(fmaxf(aB[0],  aB[1]),  fmaxf(aB[2],  aB[3]));
    float b1 = fmaxf(fmaxf(aB[4],  aB[5]),  fmaxf(aB[6],  aB[7]));
    float b2 = fmaxf(fmaxf(aB[8],  aB[9]),  fmaxf(aB[10], aB[11]));
    float b3 = fmaxf(fmaxf(aB[12], aB[13]), fmaxf(aB[14], aB[15]));
    smaxB = fmaxf(smaxB, fmaxf(fmaxf(b0, b1), fmaxf(b2, b3)));
  }
  sm[ln][qg * 2 + hi]      = smaxA;
  sm[32 + ln][qg * 2 + hi] = smaxB;
  __syncthreads();

  // tau[row] = 8th-largest of the 32 strip maxes
  if (t < 64) {
    float rv[8];
    #pragma unroll
    for (int j = 0; j < 8; ++j) rv[j] = NEG_INF;
    #pragma unroll
    for (int s = 0; s < 32; ++s) {
      float x = sm[t][s];
      if (x > rv[7]) insert8v(rv, x);
    }
    tau[t] = rv[7];
  }
  __syncthreads();

  // ---- Pass 2: recompute + compact candidates >= tau ----------------------
  const float tlA = tau[ln];
  const float tlB = tau[32 + ln];
  for (int t8 = 0; t8 < 8; ++t8) {
    const ushort* tb = ktile + (size_t)t8 * 2048;
    bf16x8 k0 = *reinterpret_cast<const bf16x8*>(tb +        kg * 8);
    bf16x8 k1 = *reinterpret_cast<const bf16x8*>(tb +  512 + kg * 8);
    bf16x8 k2 = *reinterpret_cast<const bf16x8*>(tb + 1024 + kg * 8);
    bf16x8 k3 = *reinterpret_cast<const bf16x8*>(tb + 1536 + kg * 8);

    f32x16 aA = {0.f,0.f,0.f,0.f,0.f,0.f,0.f,0.f,0.f,0.f,0.f,0.f,0.f,0.f,0.f,0.f};
    f32x16 aB = {0.f,0.f,0.f,0.f,0.f,0.f,0.f,0.f,0.f,0.f,0.f,0.f,0.f,0.f,0.f,0.f};
    aA = __builtin_amdgcn_mfma_f32_32x32x16_bf16(k0, qfA0, aA, 0, 0, 0);
    aA = __builtin_amdgcn_mfma_f32_32x32x16_bf16(k1, qfA1, aA, 0, 0, 0);
    aA = __builtin_amdgcn_mfma_f32_32x32x16_bf16(k2, qfA2, aA, 0, 0, 0);
    aA = __builtin_amdgcn_mfma_f32_32x32x16_bf16(k3, qfA3, aA, 0, 0, 0);
    aB = __builtin_amdgcn_mfma_f32_32x32x16_bf16(k0, qfB0, aB, 0, 0, 0);
    aB = __builtin_amdgcn_mfma_f32_32x32x16_bf16(k1, qfB1, aB, 0, 0, 0);
    aB = __builtin_amdgcn_mfma_f32_32x32x16_bf16(k2, qfB2, aB, 0, 0, 0);
    aB = __builtin_amdgcn_mfma_f32_32x32x16_bf16(k3, qfB3, aB, 0, 0, 0);

    const int kb0 = qg * 256 + t8 * 32 + 4 * hi;
#define CHKA(r) { float x_ = aA[r]; \
                  if (x_ >= tlA) { \
                    int p_ = atomicAdd(&cnt[ln], 1); \
                    if (p_ < CAP) cand[ln][p_] = kb0 + ((r) & 3) + 8 * ((r) >> 2); } }
#define CHKB(r) { float x_ = aB[r]; \
                  if (x_ >= tlB) { \
                    int p_ = atomicAdd(&cnt[32 + ln], 1); \
                    if (p_ < CAP) cand[32 + ln][p_] = kb0 + ((r) & 3) + 8 * ((r) >> 2); } }
    CHKA(0)  CHKA(1)  CHKA(2)  CHKA(3)
    CHKA(4)  CHKA(5)  CHKA(6)  CHKA(7)
    CHKA(8)  CHKA(9)  CHKA(10) CHKA(11)
    CHKA(12) CHKA(13) CHKA(14) CHKA(15)
    CHKB(0)  CHKB(1)  CHKB(2)  CHKB(3)
    CHKB(4)  CHKB(5)  CHKB(6)  CHKB(7)
    CHKB(8)  CHKB(9)  CHKB(10) CHKB(11)
    CHKB(12) CHKB(13) CHKB(14) CHKB(15)
#undef CHKA
#undef CHKB
  }
  __syncthreads();

  // ---- exact f32 rescore (bit-identical blocked order) --------------------
  {
    int row = t >> 4, j0 = t & 15;
    int n = min(cnt[row], CAP);
    for (int jj = j0; jj < n; jj += 16) {
      int idx = cand[row][jj];
      const float* kcol = kh + ((size_t)b * NK + idx) * INNER;
      float acc = 0.f;
      #pragma unroll
      for (int dd = 0; dd < INNER; dd += 4) {
        v4f kv = *reinterpret_cast<const v4f*>(kcol + dd);
        v4f qv = *reinterpret_cast<const v4f*>(&qhf[row][dd]);
        float bs = qv[0] * kv[0];
        bs = fmaf(qv[1], kv[1], bs);
        bs = fmaf(qv[2], kv[2], bs);
        bs = fmaf(qv[3], kv[3], bs);
        acc += bs;
      }
      exactv[row][jj] = acc;
    }
  }
  __syncthreads();

  // ---- top-5 of exact scores + softmax ------------------------------------
  if (t < 64) {
    int n = min(cnt[t], CAP);
    float rv[5]; int ri[5];
    #pragma unroll
    for (int j = 0; j < 5; ++j) { rv[j] = NEG_INF; ri[j] = 0; }
    for (int j = 0; j < n; ++j) {
      float x = exactv[t][j];
      if (x > rv[4]) insert5(rv, ri, x, cand[t][j]);
    }
    bool inc4 = (rv[4] >= rv[3]);
    float e1 = expf(rv[1] - rv[0]);
    float e2 = expf(rv[2] - rv[0]);
    float e3 = expf(rv[3] - rv[0]);
    float e4 = inc4 ? expf(rv[4] - rv[0]) : 0.0f;
    float inv = 1.0f / (1.0f + e1 + e2 + e3 + e4);
    w5[t][0] = inv;      w5[t][1] = e1 * inv;  w5[t][2] = e2 * inv;
    w5[t][3] = e3 * inv; w5[t][4] = e4 * inv;
    #pragma unroll
    for (int j = 0; j < 5; ++j) id5[t][j] = ri[j];
    id5[t][5] = inc4 ? 5 : 4;
  }
  __syncthreads();

  // ---- scattered weight stores (zeros from projfill, stream-ordered) ------
  if (t < 320) {
    int row = t / 5, j = t % 5;
    if (j < id5[row][5]) {
      float* obase = out + ((size_t)b * NQ + q0) * (size_t)NK;
      obase[(size_t)row * NK + id5[row][j]] = w5[row][j];
    }
  }
}

extern "C" void kernel_launch(void* const* d_in, const int* in_sizes, int n_in,
                              void* d_out, int out_size, void* d_ws, size_t ws_size,
                              hipStream_t stream) {
  const float* q  = (const float*)d_in[0];
  const float* k  = (const float*)d_in[1];
  const float* Wq = (const float*)d_in[3];
  const float* Wk = (const float*)d_in[4];

  const size_t NE = (size_t)BATCH * NQ * INNER;     // 1,048,576 per array
  float*  qh  = (float*)d_ws;                       // 4 MB
  float*  kh  = qh + NE;                            // 4 MB
  ushort* qhb = (ushort*)(kh + NE);                 // 2 MB
  ushort* khb = qhb + NE;                           // 2 MB (fragment-major)

  projfill_kernel<<<3072, 256, 0, stream>>>(q, k, Wq, Wk, qh, kh, qhb, khb,
                                            (float*)d_out);
  filter_kernel<<<256, 1024, 0, stream>>>(qhb, khb, qh, kh, (float*)d_out);
}

// Round 18
// 124.939 us; speedup vs baseline: 1.1849x; 1.1849x over previous
//
#include <hip/hip_runtime.h>
#include <hip/hip_bf16.h>
#include <math.h>

typedef float v4f __attribute__((ext_vector_type(4)));
typedef short bf16x8 __attribute__((ext_vector_type(8)));   // 8 bf16 (4 VGPR)
typedef float f32x16 __attribute__((ext_vector_type(16)));

#define BATCH 4
#define NQ 4096
#define NK 4096
#define DIM 256
#define INNER 64
#define NEG_INF (-3.0e38f)
#define CAP 64

// ---------- K1: fused q/k projection (f32 + bf16; khb fragment-major) --------
__global__ __launch_bounds__(256) void proj_kernel(
    const float* __restrict__ q, const float* __restrict__ k,
    const float* __restrict__ Wq, const float* __restrict__ Wk,
    float* __restrict__ qh, float* __restrict__ kh,
    ushort* __restrict__ qhb, ushort* __restrict__ khb)
{
  __shared__ float xs[32 * 260];
  const int bid = blockIdx.x;
  const bool isq = bid < 512;
  const float* X   = isq ? q : k;
  const float* W   = isq ? Wq : Wk;
  float*   out     = isq ? qh : kh;
  const float scale = isq ? 0.125f : 1.0f;
  const int row0 = (isq ? bid : bid - 512) * 32;
  const int t = threadIdx.x;

  #pragma unroll
  for (int it = 0; it < 8; ++it) {
    int idx = it * 256 + t;
    int r = idx >> 6, dq = idx & 63;
    v4f v = *reinterpret_cast<const v4f*>(X + (size_t)(row0 + r) * DIM + dq * 4);
    *reinterpret_cast<v4f*>(&xs[r * 260 + dq * 4]) = v;
  }
  __syncthreads();

  const int i0 = (t & 15) * 4;
  const int rg = t >> 4;
  float acc[2][4];
  #pragma unroll
  for (int p = 0; p < 2; ++p)
    #pragma unroll
    for (int i = 0; i < 4; ++i) acc[p][i] = 0.f;

  for (int d0 = 0; d0 < DIM; d0 += 4) {
    v4f w0 = *reinterpret_cast<const v4f*>(W + (d0 + 0) * INNER + i0);
    v4f w1 = *reinterpret_cast<const v4f*>(W + (d0 + 1) * INNER + i0);
    v4f w2 = *reinterpret_cast<const v4f*>(W + (d0 + 2) * INNER + i0);
    v4f w3 = *reinterpret_cast<const v4f*>(W + (d0 + 3) * INNER + i0);
    #pragma unroll
    for (int p = 0; p < 2; ++p) {
      v4f x = *reinterpret_cast<const v4f*>(&xs[(rg + 16 * p) * 260 + d0]);
      #pragma unroll
      for (int i = 0; i < 4; ++i) {
        float bs = x[0] * w0[i];                 // bit-exact blocked order
        bs = fmaf(x[1], w1[i], bs);
        bs = fmaf(x[2], w2[i], bs);
        bs = fmaf(x[3], w3[i], bs);
        acc[p][i] += bs;
      }
    }
  }

  const int d  = i0 >> 4;
  const int hi = (i0 >> 3) & 1;
  const int e0 = i0 & 7;
  #pragma unroll
  for (int p = 0; p < 2; ++p) {
    v4f o;
    ushort ob[4];
    #pragma unroll
    for (int i = 0; i < 4; ++i) {
      o[i] = acc[p][i] * scale;
      __hip_bfloat16 h = __float2bfloat16(o[i]);
      ob[i] = *reinterpret_cast<ushort*>(&h);
    }
    int rr = rg + 16 * p;
    size_t row = (size_t)(row0 + rr);
    *reinterpret_cast<v4f*>(out + row * INNER + i0) = o;
    if (isq) {
      *reinterpret_cast<uint2*>(qhb + row * INNER + i0) =
          *reinterpret_cast<uint2*>(ob);
    } else {
      size_t off = (size_t)(bid - 512) * 2048 + d * 512 + hi * 256 + rr * 8 + e0;
      *reinterpret_cast<uint2*>(khb + off) = *reinterpret_cast<uint2*>(ob);
    }
  }
}

// ---------- cold-path sorted inserts -----------------------------------------
__device__ __forceinline__ void insert5(float (&v)[5], int (&ix)[5], float x, int xi) {
  bool g0 = x > v[0], g1 = x > v[1], g2 = x > v[2], g3 = x > v[3];
  v[4]  = g3 ? v[3] : x;                 ix[4] = g3 ? ix[3] : xi;
  v[3]  = g3 ? (g2 ? v[2] : x) : v[3];   ix[3] = g3 ? (g2 ? ix[2] : xi) : ix[3];
  v[2]  = g2 ? (g1 ? v[1] : x) : v[2];   ix[2] = g2 ? (g1 ? ix[1] : xi) : ix[2];
  v[1]  = g1 ? (g0 ? v[0] : x) : v[1];   ix[1] = g1 ? (g0 ? ix[0] : xi) : ix[1];
  v[0]  = g0 ? x : v[0];                 ix[0] = g0 ? xi : ix[0];
}

__device__ __forceinline__ void insert8v(float (&v)[8], float x) {
  bool g0 = x > v[0], g1 = x > v[1], g2 = x > v[2], g3 = x > v[3];
  bool g4 = x > v[4], g5 = x > v[5], g6 = x > v[6];
  v[7] = g6 ? v[6] : x;
  v[6] = g6 ? (g5 ? v[5] : x) : v[6];
  v[5] = g5 ? (g4 ? v[4] : x) : v[5];
  v[4] = g4 ? (g3 ? v[3] : x) : v[4];
  v[3] = g3 ? (g2 ? v[2] : x) : v[3];
  v[2] = g2 ? (g1 ? v[1] : x) : v[2];
  v[1] = g1 ? (g0 ? v[0] : x) : v[1];
  v[0] = g0 ? x : v[0];
}

// ---------- K2: 2-pass MFMA filter, 1-deep fragment PREFETCH + zeros ---------
// r16 structure (512 blocks x 512 thr, own-row zeros, fragment-major khb),
// plus: iteration c issues the 4 fragment loads for tile c+1 BEFORE the MFMAs
// on tile c's registers -> L2/L3 latency hides under compute+stores instead
// of being exposed serially each iteration (the r6 spill trap is avoided:
// hot loop is all named scalars/vectors, +16 VGPR only).
__global__ __launch_bounds__(512) void filter_kernel(
    const ushort* __restrict__ qhb, const ushort* __restrict__ khb,
    const float* __restrict__ qh, const float* __restrict__ kh,
    float* __restrict__ out)
{
  __shared__ float qhf[32][68];
  __shared__ float sm[32][16];
  __shared__ float tau[32];
  __shared__ int   cnt[32];
  __shared__ int   cand[32][CAP];
  __shared__ float exactv[32][CAP];
  __shared__ float w5[32][5];
  __shared__ int   id5[32][6];

  const int t   = threadIdx.x;
  const int bid = blockIdx.x;
  const int wg  = (bid & 7) * 64 + (bid >> 3);   // XCD swizzle (512 = 8*64)
  const int b   = wg >> 7;
  const int q0  = (wg & 127) * 32;
  const int qg  = t >> 6;                        // wave 0..7
  const int kg  = t & 63;
  const int ln  = kg & 31;
  const int hi  = kg >> 5;

  float* obase = out + ((size_t)b * NQ + q0) * (size_t)NK;
  const v4f z = {0.f, 0.f, 0.f, 0.f};

  if (t < 256) {
    int row = t >> 3, c8 = (t & 7) * 8;
    const float* src = qh + ((size_t)b * NQ + q0 + row) * INNER + c8;
    *reinterpret_cast<v4f*>(&qhf[row][c8])     = *reinterpret_cast<const v4f*>(src);
    *reinterpret_cast<v4f*>(&qhf[row][c8 + 4]) = *reinterpret_cast<const v4f*>(src + 4);
  }
  if (t < 32) cnt[t] = 0;

  const ushort* qptr = qhb + ((size_t)b * NQ + q0 + ln) * INNER + hi * 8;
  bf16x8 qf0 = *reinterpret_cast<const bf16x8*>(qptr);
  bf16x8 qf1 = *reinterpret_cast<const bf16x8*>(qptr + 16);
  bf16x8 qf2 = *reinterpret_cast<const bf16x8*>(qptr + 32);
  bf16x8 qf3 = *reinterpret_cast<const bf16x8*>(qptr + 48);

  const ushort* ktile = khb + ((size_t)b * 128 + qg * 16) * 2048;

  // ---- Pass 1: strip max, prefetched fragments, interleaved zeros ---------
  float smax = NEG_INF;
  {
    bf16x8 n0 = *reinterpret_cast<const bf16x8*>(ktile +        kg * 8);
    bf16x8 n1 = *reinterpret_cast<const bf16x8*>(ktile +  512 + kg * 8);
    bf16x8 n2 = *reinterpret_cast<const bf16x8*>(ktile + 1024 + kg * 8);
    bf16x8 n3 = *reinterpret_cast<const bf16x8*>(ktile + 1536 + kg * 8);
    for (int t16 = 0; t16 < 16; ++t16) {
      bf16x8 k0 = n0, k1 = n1, k2 = n2, k3 = n3;
      const ushort* nb = ktile + (size_t)(t16 + 1 < 16 ? t16 + 1 : 15) * 2048;
      n0 = *reinterpret_cast<const bf16x8*>(nb +        kg * 8);
      n1 = *reinterpret_cast<const bf16x8*>(nb +  512 + kg * 8);
      n2 = *reinterpret_cast<const bf16x8*>(nb + 1024 + kg * 8);
      n3 = *reinterpret_cast<const bf16x8*>(nb + 1536 + kg * 8);

      *reinterpret_cast<v4f*>(obase + (size_t)t16 * 4096 + t * 8)     = z;
      *reinterpret_cast<v4f*>(obase + (size_t)t16 * 4096 + t * 8 + 4) = z;

      f32x16 acc = {0.f, 0.f, 0.f, 0.f, 0.f, 0.f, 0.f, 0.f,
                    0.f, 0.f, 0.f, 0.f, 0.f, 0.f, 0.f, 0.f};
      acc = __builtin_amdgcn_mfma_f32_32x32x16_bf16(k0, qf0, acc, 0, 0, 0);
      acc = __builtin_amdgcn_mfma_f32_32x32x16_bf16(k1, qf1, acc, 0, 0, 0);
      acc = __builtin_amdgcn_mfma_f32_32x32x16_bf16(k2, qf2, acc, 0, 0, 0);
      acc = __builtin_amdgcn_mfma_f32_32x32x16_bf16(k3, qf3, acc, 0, 0, 0);

      float m0 = fmaxf(fmaxf(acc[0],  acc[1]),  fmaxf(acc[2],  acc[3]));
      float m1 = fmaxf(fmaxf(acc[4],  acc[5]),  fmaxf(acc[6],  acc[7]));
      float m2 = fmaxf(fmaxf(acc[8],  acc[9]),  fmaxf(acc[10], acc[11]));
      float m3 = fmaxf(fmaxf(acc[12], acc[13]), fmaxf(acc[14], acc[15]));
      smax = fmaxf(smax, fmaxf(fmaxf(m0, m1), fmaxf(m2, m3)));
    }
  }
  sm[ln][qg * 2 + hi] = smax;
  __syncthreads();

  if (t < 32) {
    float rv[8];
    #pragma unroll
    for (int j = 0; j < 8; ++j) rv[j] = NEG_INF;
    #pragma unroll
    for (int s = 0; s < 16; ++s) {
      float x = sm[t][s];
      if (x > rv[7]) insert8v(rv, x);
    }
    tau[t] = rv[7];
  }
  __syncthreads();

  // ---- Pass 2: prefetched recompute + compact >= tau + zeros ---------------
  const float tl = tau[ln];
  {
    bf16x8 n0 = *reinterpret_cast<const bf16x8*>(ktile +        kg * 8);
    bf16x8 n1 = *reinterpret_cast<const bf16x8*>(ktile +  512 + kg * 8);
    bf16x8 n2 = *reinterpret_cast<const bf16x8*>(ktile + 1024 + kg * 8);
    bf16x8 n3 = *reinterpret_cast<const bf16x8*>(ktile + 1536 + kg * 8);
    for (int t16 = 0; t16 < 16; ++t16) {
      bf16x8 k0 = n0, k1 = n1, k2 = n2, k3 = n3;
      const ushort* nb = ktile + (size_t)(t16 + 1 < 16 ? t16 + 1 : 15) * 2048;
      n0 = *reinterpret_cast<const bf16x8*>(nb +        kg * 8);
      n1 = *reinterpret_cast<const bf16x8*>(nb +  512 + kg * 8);
      n2 = *reinterpret_cast<const bf16x8*>(nb + 1024 + kg * 8);
      n3 = *reinterpret_cast<const bf16x8*>(nb + 1536 + kg * 8);

      *reinterpret_cast<v4f*>(obase + (size_t)(16 + t16) * 4096 + t * 8)     = z;
      *reinterpret_cast<v4f*>(obase + (size_t)(16 + t16) * 4096 + t * 8 + 4) = z;

      f32x16 acc = {0.f, 0.f, 0.f, 0.f, 0.f, 0.f, 0.f, 0.f,
                    0.f, 0.f, 0.f, 0.f, 0.f, 0.f, 0.f, 0.f};
      acc = __builtin_amdgcn_mfma_f32_32x32x16_bf16(k0, qf0, acc, 0, 0, 0);
      acc = __builtin_amdgcn_mfma_f32_32x32x16_bf16(k1, qf1, acc, 0, 0, 0);
      acc = __builtin_amdgcn_mfma_f32_32x32x16_bf16(k2, qf2, acc, 0, 0, 0);
      acc = __builtin_amdgcn_mfma_f32_32x32x16_bf16(k3, qf3, acc, 0, 0, 0);

      const int kb0 = qg * 512 + t16 * 32 + 4 * hi;
#define CHK(r) { float x_ = acc[r]; \
                 if (x_ >= tl) { \
                   int p_ = atomicAdd(&cnt[ln], 1); \
                   if (p_ < CAP) cand[ln][p_] = kb0 + ((r) & 3) + 8 * ((r) >> 2); } }
      CHK(0)  CHK(1)  CHK(2)  CHK(3)
      CHK(4)  CHK(5)  CHK(6)  CHK(7)
      CHK(8)  CHK(9)  CHK(10) CHK(11)
      CHK(12) CHK(13) CHK(14) CHK(15)
#undef CHK
    }
  }
  __syncthreads();   // all zero stores drained (per-wave vmcnt(0) + barrier)

  // ---- exact f32 rescore (bit-identical blocked order) --------------------
  {
    int row = t >> 4, j0 = t & 15;
    int n = min(cnt[row], CAP);
    for (int jj = j0; jj < n; jj += 16) {
      int idx = cand[row][jj];
      const float* kcol = kh + ((size_t)b * NK + idx) * INNER;
      float acc = 0.f;
      #pragma unroll
      for (int dd = 0; dd < INNER; dd += 4) {
        v4f kv = *reinterpret_cast<const v4f*>(kcol + dd);
        v4f qv = *reinterpret_cast<const v4f*>(&qhf[row][dd]);
        float bs = qv[0] * kv[0];
        bs = fmaf(qv[1], kv[1], bs);
        bs = fmaf(qv[2], kv[2], bs);
        bs = fmaf(qv[3], kv[3], bs);
        acc += bs;
      }
      exactv[row][jj] = acc;
    }
  }
  __syncthreads();

  // ---- top-5 of exact scores + softmax ------------------------------------
  if (t < 32) {
    int n = min(cnt[t], CAP);
    float rv[5]; int ri[5];
    #pragma unroll
    for (int j = 0; j < 5; ++j) { rv[j] = NEG_INF; ri[j] = 0; }
    for (int j = 0; j < n; ++j) {
      float x = exactv[t][j];
      if (x > rv[4]) insert5(rv, ri, x, cand[t][j]);
    }
    bool inc4 = (rv[4] >= rv[3]);
    float e1 = expf(rv[1] - rv[0]);
    float e2 = expf(rv[2] - rv[0]);
    float e3 = expf(rv[3] - rv[0]);
    float e4 = inc4 ? expf(rv[4] - rv[0]) : 0.0f;
    float inv = 1.0f / (1.0f + e1 + e2 + e3 + e4);
    w5[t][0] = inv;      w5[t][1] = e1 * inv;  w5[t][2] = e2 * inv;
    w5[t][3] = e3 * inv; w5[t][4] = e4 * inv;
    #pragma unroll
    for (int j = 0; j < 5; ++j) id5[t][j] = ri[j];
    id5[t][5] = inc4 ? 5 : 4;
  }
  __syncthreads();

  // ---- scattered weight stores (own rows only; zeros already drained) -----
  if (t < 160) {
    int row = t / 5, j = t % 5;
    if (j < id5[row][5])
      obase[(size_t)row * NK + id5[row][j]] = w5[row][j];
  }
}

extern "C" void kernel_launch(void* const* d_in, const int* in_sizes, int n_in,
                              void* d_out, int out_size, void* d_ws, size_t ws_size,
                              hipStream_t stream) {
  const float* q  = (const float*)d_in[0];
  const float* k  = (const float*)d_in[1];
  const float* Wq = (const float*)d_in[3];
  const float* Wk = (const float*)d_in[4];

  const size_t NE = (size_t)BATCH * NQ * INNER;     // 1,048,576 per array
  float*  qh  = (float*)d_ws;                       // 4 MB
  float*  kh  = qh + NE;                            // 4 MB
  ushort* qhb = (ushort*)(kh + NE);                 // 2 MB
  ushort* khb = qhb + NE;                           // 2 MB (fragment-major)

  proj_kernel<<<1024, 256, 0, stream>>>(q, k, Wq, Wk, qh, kh, qhb, khb);
  filter_kernel<<<512, 512, 0, stream>>>(qhb, khb, qh, kh, (float*)d_out);
}